// Round 9
// baseline (64.385 us; speedup 1.0000x reference)
//
#include <hip/hip_runtime.h>
#include <hip/hip_bf16.h>
#include <math.h>

// DifferentiableRAM: out[b,c,n,m] = gamma[b] * sum_h Fy[b,n,h] * sum_w x[b,c,h,w] * Fx[b,m,w]
// G[bc][m][h] = (x[bc] @ Fx[b]^T)^T ; out[bc][n][m] = gamma * Fy[b] @ G[bc]^T
// R9: gemm1 depth-2 register k-prefetch (issue k+2 during compute k) so the
//     HBM pipeline never drains; named staging sets (no runtime reg indexing).
// ws: Fx_b 8MB | Fy_b 8MB | G 25.2MB => 41.2 MB

namespace {

typedef __attribute__((ext_vector_type(8))) short v8s;    // 8 bf16
typedef __attribute__((ext_vector_type(4))) short v4s;    // 4 bf16 (8B)
typedef __attribute__((ext_vector_type(4))) float f32x4;  // MFMA C/D frag

constexpr int Bn = 32;
constexpr int Cc = 3;
constexpr int HW = 512;
constexpr int Nn = 256;
constexpr float SMALLF = 1e-4f;

__device__ inline unsigned short f2bf(float f) {
    __hip_bfloat16 h = __float2bfloat16(f);
    union { __hip_bfloat16 h; unsigned short u; } c;
    c.h = h;
    return c.u;
}

// bijective XCD swizzle (grid % 8 == 0)
__device__ inline int xcd_swz(int bid, int nwg) {
    return (bid & 7) * (nwg >> 3) + (bid >> 3);
}

// ---------------- Kernel 1: Gaussian filterbanks (bf16 out) ---------------
__global__ __launch_bounds__(256) void fb_kernel(const float* __restrict__ p,
                                                 unsigned short* __restrict__ Fx,
                                                 unsigned short* __restrict__ Fy) {
    const int wid  = threadIdx.x >> 6;
    const int lane = threadIdx.x & 63;
    const int rid  = blockIdx.x * 4 + wid;        // 0..16383
    const int which = rid >> 13;
    const int r = rid & 8191;
    const int b = r >> 8;
    const int n = r & 255;

    const float* pb = p + b * 5;
    const float sigma2 = expf(pb[2]);
    const float delta  = expf(pb[3]) * (511.0f / 255.0f);
    const float g = (which == 0) ? (HW * (pb[0] + 1.0f) * 0.5f)
                                 : (HW * (pb[1] + 1.0f) * 0.5f);
    const float mu = g + delta * ((float)n - 128.5f);
    const float inv2s = 0.5f / sigma2;

    float f[8];
    float sum = 0.0f;
#pragma unroll
    for (int q = 0; q < 8; ++q) {
        float a = (float)(q * 64 + lane);
        float d = a - mu;
        f[q] = expf(-d * d * inv2s);
        sum += f[q];
    }
#pragma unroll
    for (int s = 1; s < 64; s <<= 1) sum += __shfl_xor(sum, s, 64);
    const float inv = 1.0f / (sum + SMALLF);

    unsigned short* dst = ((which == 0) ? Fx : Fy) + ((size_t)(b * Nn + n)) * HW;
#pragma unroll
    for (int q = 0; q < 8; ++q) dst[q * 64 + lane] = f2bf(f[q] * inv);
}

// ---------------- LDS helpers (XOR-swizzled) -------------------------------
// byte(row, kbyte) = row*128 + (kbyte ^ ((row&7)<<4)); tile = rows x 64 bf16.
__device__ inline v8s frag_read(const unsigned short* __restrict__ lds, int row, int kk, int lk) {
    int byte = row * 128 + (((kk * 64) + lk * 16) ^ ((row & 7) << 4));
    return *(const v8s*)((const char*)lds + byte);
}

// ---------------- Kernel 2: G[bc][m][h] = (x[bc] @ Fx_b[b]^T)^T ------------
// M=h (tile 128), N=m (tile 256 = full), K=w (512). 512 thr, 8 waves (2h x 4m).
// x read exactly once. Depth-2 register prefetch: LOAD(k+2) issued before
// COMPUTE(k); loop unrolled x2 with literal set indices (no scratch).
// grid = 384 (1D, XCD-swizzled): wg -> bc*4 + htile
__global__ __launch_bounds__(512, 1) void gemm1_kernel(const float* __restrict__ x,
                                                       const unsigned short* __restrict__ Fx_b,
                                                       unsigned short* __restrict__ G) {
    __shared__ unsigned short As[128 * 64];   // h rows (converted bf16)
    __shared__ unsigned short Bs[256 * 64];   // m rows
    const int t = threadIdx.x;
    const int wg = xcd_swz(blockIdx.x, 384);
    const int bc = wg >> 2, b = bc / 3;
    const int h0 = (wg & 3) * 128;

    const float* Ag = x + (size_t)bc * HW * HW + (size_t)h0 * HW;
    const unsigned short* Bg = Fx_b + (size_t)b * Nn * HW;

    const int wid = t >> 6, lane = t & 63, lr = lane & 15, lk = lane >> 4;
    const int wm = (wid >> 2) * 64;   // h-offset within 128
    const int wn = (wid & 3) * 64;    // m-offset within 256

    const int oct = t & 7;            // k-octet (8 elems)
    const int rowb = t >> 3;          // 0..63

    f32x4 acc[4][4];
#pragma unroll
    for (int i = 0; i < 4; ++i)
#pragma unroll
        for (int j = 0; j < 4; ++j) acc[i][j] = (f32x4){0.f, 0.f, 0.f, 0.f};

    // two staging sets; all indices compile-time constant
    float4 xa[2][2][2];   // [set][rowblk][half]: 2 rows x 8 floats
    v8s    fxv[2][4];     // [set][rowblk]: 4 rows x 8 bf16

#define G1_LOAD(S, K0)                                                           \
    {                                                                            \
        _Pragma("unroll")                                                        \
        for (int rb = 0; rb < 2; ++rb) {                                         \
            const float* s_ = Ag + (size_t)(rowb + 64 * rb) * HW + (K0) + oct * 8; \
            xa[S][rb][0] = *(const float4*)s_;                                   \
            xa[S][rb][1] = *(const float4*)(s_ + 4);                             \
        }                                                                        \
        _Pragma("unroll")                                                        \
        for (int rb = 0; rb < 4; ++rb)                                           \
            fxv[S][rb] = *(const v8s*)(Bg + (size_t)(rowb + 64 * rb) * HW + (K0) + oct * 8); \
    }

#define G1_WRITE(S)                                                              \
    {                                                                            \
        _Pragma("unroll")                                                        \
        for (int rb = 0; rb < 2; ++rb) {                                         \
            int row = rowb + 64 * rb;                                            \
            unsigned short q_[8] = {f2bf(xa[S][rb][0].x), f2bf(xa[S][rb][0].y),  \
                                    f2bf(xa[S][rb][0].z), f2bf(xa[S][rb][0].w),  \
                                    f2bf(xa[S][rb][1].x), f2bf(xa[S][rb][1].y),  \
                                    f2bf(xa[S][rb][1].z), f2bf(xa[S][rb][1].w)}; \
            int byte = row * 128 + ((oct * 16) ^ ((row & 7) << 4));              \
            *(v8s*)((char*)As + byte) = *(const v8s*)q_;                         \
        }                                                                        \
        _Pragma("unroll")                                                        \
        for (int rb = 0; rb < 4; ++rb) {                                         \
            int row = rowb + 64 * rb;                                            \
            int byte = row * 128 + ((oct * 16) ^ ((row & 7) << 4));              \
            *(v8s*)((char*)Bs + byte) = fxv[S][rb];                              \
        }                                                                        \
    }

#define G1_COMPUTE()                                                             \
    {                                                                            \
        _Pragma("unroll")                                                        \
        for (int kk = 0; kk < 2; ++kk) {                                         \
            v8s af[4], bf[4];                                                    \
            _Pragma("unroll")                                                    \
            for (int mi = 0; mi < 4; ++mi) af[mi] = frag_read(As, wm + mi * 16 + lr, kk, lk); \
            _Pragma("unroll")                                                    \
            for (int ni = 0; ni < 4; ++ni) bf[ni] = frag_read(Bs, wn + ni * 16 + lr, kk, lk); \
            _Pragma("unroll")                                                    \
            for (int mi = 0; mi < 4; ++mi)                                       \
                _Pragma("unroll")                                                \
                for (int ni = 0; ni < 4; ++ni)                                   \
                    acc[mi][ni] = __builtin_amdgcn_mfma_f32_16x16x32_bf16(af[mi], bf[ni], acc[mi][ni], 0, 0, 0); \
        }                                                                        \
    }

    G1_LOAD(0, 0);
    G1_LOAD(1, 64);
#pragma unroll 1
    for (int ksb = 0; ksb < 8; ksb += 2) {
        __syncthreads();
        G1_WRITE(0);
        __syncthreads();
        if (ksb + 2 < 8) G1_LOAD(0, (ksb + 2) * 64);
        G1_COMPUTE();
        __syncthreads();
        G1_WRITE(1);
        __syncthreads();
        if (ksb + 3 < 8) G1_LOAD(1, (ksb + 3) * 64);
        G1_COMPUTE();
    }
#undef G1_LOAD
#undef G1_WRITE
#undef G1_COMPUTE

    // transposed store: G[m][h]; lane's 4 acc regs = 4 consecutive h -> 8B store
    unsigned short* Cg = G + (size_t)bc * Nn * HW;
#pragma unroll
    for (int mi = 0; mi < 4; ++mi)
#pragma unroll
        for (int ni = 0; ni < 4; ++ni) {
            int mg = wn + ni * 16 + lr;
            int hg = h0 + wm + mi * 16 + lk * 4;
            unsigned short q[4] = {f2bf(acc[mi][ni][0]), f2bf(acc[mi][ni][1]),
                                   f2bf(acc[mi][ni][2]), f2bf(acc[mi][ni][3])};
            *(v4s*)(Cg + (size_t)mg * HW + hg) = *(const v4s*)q;
        }
}

// ---------------- Kernel 3: out[bc][n][m] = gamma * Fy_b[b] @ G[bc]^T ------
// M=n, N=m (tiles 128x128), K=h (512). 256 thr, 4 waves (2x2), reg k-prefetch.
// grid = 384 (1D, XCD-swizzled): wg -> bc*4 + mtile*2 + ntile
__global__ __launch_bounds__(256, 2) void gemm2_kernel(const unsigned short* __restrict__ Fy_b,
                                                       const unsigned short* __restrict__ G,
                                                       const float* __restrict__ p,
                                                       float* __restrict__ out) {
    __shared__ unsigned short As[128 * 64];
    __shared__ unsigned short Bs[128 * 64];
    const int t = threadIdx.x;
    const int wg = xcd_swz(blockIdx.x, 384);
    const int bc = wg >> 2, b = bc / 3;
    const int rem = wg & 3;
    const int m0 = (rem >> 1) * 128;
    const int n0 = (rem & 1) * 128;

    const unsigned short* Ag = Fy_b + (size_t)b * Nn * HW + (size_t)n0 * HW;
    const unsigned short* Bg = G + (size_t)bc * Nn * HW + (size_t)m0 * HW;
    const float gamma = expf(p[b * 5 + 4]);

    const int wid = t >> 6, lane = t & 63, lr = lane & 15, lk = lane >> 4;
    const int wm = (wid >> 1) * 64, wn = (wid & 1) * 64;

    const int oct = t & 7;
    const int rowb = t >> 3;   // 0..31

    f32x4 acc[4][4];
#pragma unroll
    for (int i = 0; i < 4; ++i)
#pragma unroll
        for (int j = 0; j < 4; ++j) acc[i][j] = (f32x4){0.f, 0.f, 0.f, 0.f};

    v8s va[4], vb[4];

#define G2_LOAD(K0)                                                              \
    {                                                                            \
        _Pragma("unroll")                                                        \
        for (int rb = 0; rb < 4; ++rb) {                                         \
            int row = rowb + 32 * rb;                                            \
            va[rb] = *(const v8s*)(Ag + (size_t)row * HW + (K0) + oct * 8);      \
            vb[rb] = *(const v8s*)(Bg + (size_t)row * HW + (K0) + oct * 8);      \
        }                                                                        \
    }

    G2_LOAD(0);
#pragma unroll 1
    for (int ks = 0; ks < 8; ++ks) {
        __syncthreads();
#pragma unroll
        for (int rb = 0; rb < 4; ++rb) {
            int row = rowb + 32 * rb;
            int byte = row * 128 + ((oct * 16) ^ ((row & 7) << 4));
            *(v8s*)((char*)As + byte) = va[rb];
            *(v8s*)((char*)Bs + byte) = vb[rb];
        }
        __syncthreads();
        if (ks < 7) G2_LOAD((ks + 1) * 64);
#pragma unroll
        for (int kk = 0; kk < 2; ++kk) {
            v8s af[4], bf[4];
#pragma unroll
            for (int mi = 0; mi < 4; ++mi) af[mi] = frag_read(As, wm + mi * 16 + lr, kk, lk);
#pragma unroll
            for (int ni = 0; ni < 4; ++ni) bf[ni] = frag_read(Bs, wn + ni * 16 + lr, kk, lk);
#pragma unroll
            for (int mi = 0; mi < 4; ++mi)
#pragma unroll
                for (int ni = 0; ni < 4; ++ni)
                    acc[mi][ni] = __builtin_amdgcn_mfma_f32_16x16x32_bf16(af[mi], bf[ni], acc[mi][ni], 0, 0, 0);
        }
    }
#undef G2_LOAD

    float* Cg = out + (size_t)bc * Nn * Nn + (size_t)(n0 + wm) * Nn + (m0 + wn);
#pragma unroll
    for (int mi = 0; mi < 4; ++mi)
#pragma unroll
        for (int r = 0; r < 4; ++r) {
            int row = mi * 16 + lk * 4 + r;
#pragma unroll
            for (int ni = 0; ni < 4; ++ni)
                Cg[(size_t)row * Nn + ni * 16 + lr] = gamma * acc[mi][ni][r];
        }
}

} // anonymous namespace

extern "C" void kernel_launch(void* const* d_in, const int* in_sizes, int n_in,
                              void* d_out, int out_size, void* d_ws, size_t ws_size,
                              hipStream_t stream) {
    const float* x = (const float*)d_in[0];   // [32,3,512,512]
    const float* p = (const float*)d_in[1];   // [32,5]
    float* out = (float*)d_out;               // [32,3,256,256] f32

    char* ws = (char*)d_ws;
    unsigned short* Fx_b = (unsigned short*)ws;                    // 32*256*512
    unsigned short* Fy_b = Fx_b + (size_t)Bn * Nn * HW;            // 32*256*512
    unsigned short* G    = Fy_b + (size_t)Bn * Nn * HW;            // 96*256*512 ([bc][m][h])

    hipLaunchKernelGGL(fb_kernel, dim3(4096), dim3(256), 0, stream, p, Fx_b, Fy_b);
    hipLaunchKernelGGL(gemm1_kernel, dim3(384), dim3(512), 0, stream, x, Fx_b, G);
    hipLaunchKernelGGL(gemm2_kernel, dim3(384), dim3(256), 0, stream, Fy_b, G, p, out);
}